// Round 1
// baseline (377.918 us; speedup 1.0000x reference)
//
#include <hip/hip_runtime.h>
#include <math.h>

#define NN 512
#define CC 256
#define HH 8
#define DH 32

// ---------------- Kernel A: projections + Wp-fold ----------------
// block = 256 threads, handles 4 rows n0..n0+3
__global__ __launch_bounds__(256) void proj_kernel(
    const float* __restrict__ xq, const float* __restrict__ xk, const float* __restrict__ xv,
    const float* __restrict__ Wq, const float* __restrict__ bq,
    const float* __restrict__ Wk, const float* __restrict__ bk,
    const float* __restrict__ Wv, const float* __restrict__ bv,
    const float* __restrict__ Wp, const float* __restrict__ bp,
    float* __restrict__ qf, float* __restrict__ kf, float* __restrict__ vf,
    float* __restrict__ qw, float* __restrict__ qbp)
{
    __shared__ float x_lds[3][4][CC];   // 12 KB
    __shared__ float q_lds[4][CC];      // 4 KB
    const int t = threadIdx.x;
    const int n0 = blockIdx.x * 4;

    const float* xs[3] = {xq, xk, xv};
    for (int X = 0; X < 3; ++X) {
        int ni = t >> 6, c4 = (t & 63) * 4;
        float4 v = *reinterpret_cast<const float4*>(xs[X] + (size_t)(n0 + ni) * CC + c4);
        *reinterpret_cast<float4*>(&x_lds[X][ni][c4]) = v;
    }
    __syncthreads();

    const int j = t;
    const float* Ws[3] = {Wq, Wk, Wv};
    const float* bs[3] = {bq, bk, bv};
    float* outs[3] = {qf, kf, vf};
    for (int X = 0; X < 3; ++X) {
        float acc[4] = {0.f, 0.f, 0.f, 0.f};
        const float* wrow = Ws[X] + (size_t)j * CC;
        for (int k4 = 0; k4 < CC / 4; ++k4) {
            float4 wv = *reinterpret_cast<const float4*>(wrow + k4 * 4);
            #pragma unroll
            for (int ni = 0; ni < 4; ++ni) {
                const float* xr = &x_lds[X][ni][k4 * 4];
                acc[ni] += xr[0] * wv.x + xr[1] * wv.y + xr[2] * wv.z + xr[3] * wv.w;
            }
        }
        float b = bs[X][j];
        for (int ni = 0; ni < 4; ++ni) {
            float val = acc[ni] + b;
            outs[X][(size_t)(n0 + ni) * CC + j] = val;
            if (X == 0) q_lds[ni][j] = val;
        }
    }
    __syncthreads();

    // qW[n][h][K] = sum_c q[n, h*32+c] * Wp[h*32+c, K]   (thread j = K, coalesced)
    {
        const int K = t;
        for (int h = 0; h < HH; ++h) {
            float acc[4] = {0.f, 0.f, 0.f, 0.f};
            for (int c = 0; c < DH; ++c) {
                float w = Wp[(size_t)(h * DH + c) * CC + K];
                #pragma unroll
                for (int ni = 0; ni < 4; ++ni)
                    acc[ni] += q_lds[ni][h * DH + c] * w;
            }
            for (int ni = 0; ni < 4; ++ni)
                qw[((size_t)(n0 + ni) * HH + h) * CC + K] = acc[ni];
        }
    }
    // qbp[n][h] = dot(q_head, bp_head)
    if (t < 32) {
        int ni = t >> 3, h = t & 7;
        float s = 0.f;
        for (int c = 0; c < DH; ++c) s += q_lds[ni][h * DH + c] * bp[h * DH + c];
        qbp[(size_t)(n0 + ni) * HH + h] = s;
    }
}

// ---------------- Kernel B: fused scores + softmax + hidden ----------------
// one block per n, 512 threads (8 waves)
__global__ __launch_bounds__(512, 4) void attn_kernel(
    const float* __restrict__ E, const float* __restrict__ qf,
    const float* __restrict__ kf, const float* __restrict__ vf,
    const float* __restrict__ qw, const float* __restrict__ qbp,
    float* __restrict__ out_hidden, float* __restrict__ out_attn)
{
    const int n = blockIdx.x;
    const int t = threadIdx.x;

    __shared__ float qw_lds[HH * 272];   // swizzled: idx = h*272 + C + (C>>6)*4
    __shared__ float s_lds[HH * 516];    // scores / attn, padded stride 516
    __shared__ float q_lds[CC];
    __shared__ float qbp_lds[HH];
    __shared__ float part_lds[8 * 256];  // hidden partials

    // stage qW (swizzled so the 4 C-quarters land on distinct bank groups)
    {
        int h = t >> 6, C4 = (t & 63) * 4;
        float4 v = *reinterpret_cast<const float4*>(qw + ((size_t)n * HH + h) * CC + C4);
        int idx = h * 272 + C4 + (C4 >> 6) * 4;
        *reinterpret_cast<float4*>(&qw_lds[idx]) = v;
    }
    if (t < 64) {
        float4 v = *reinterpret_cast<const float4*>(qf + (size_t)n * CC + t * 4);
        *reinterpret_cast<float4*>(&q_lds[t * 4]) = v;
    }
    if (t < HH) qbp_lds[t] = qbp[(size_t)n * HH + t];
    __syncthreads();

    const int cq = t & 3;        // C-quarter: C in [cq*64, cq*64+64)
    const int mg = t >> 2;       // 0..127; handles m = mg + j*128
    float acc[HH][4];
    #pragma unroll
    for (int h = 0; h < HH; ++h)
        #pragma unroll
        for (int jj = 0; jj < 4; ++jj) acc[h][jj] = 0.f;

    // scores_e: this lane's C-quarter covers heads 2cq, 2cq+1 (k is L2-resident)
    #pragma unroll
    for (int hh = 0; hh < 2; ++hh) {
        int h = 2 * cq + hh;
        int C0 = h * DH;
        #pragma unroll
        for (int jj = 0; jj < 4; ++jj) {
            int m = mg + jj * 128;
            const float* krow = kf + (size_t)m * CC + C0;
            float s = 0.f;
            #pragma unroll
            for (int c4 = 0; c4 < DH / 4; ++c4) {
                float4 kv = *reinterpret_cast<const float4*>(krow + c4 * 4);
                const float* qr = &q_lds[C0 + c4 * 4];
                s += qr[0] * kv.x + qr[1] * kv.y + qr[2] * kv.z + qr[3] * kv.w;
            }
            acc[h][jj] += s;
        }
    }

    // scores_p: stream E[n, m, C-quarter], 8 head-dots per float4
    {
        const int Cbase = cq * 64;
        const float* Ebase = E + (size_t)n * NN * CC;
        for (int c4 = 0; c4 < 16; ++c4) {
            const int Cc = Cbase + c4 * 4;
            float4 ev[4];
            #pragma unroll
            for (int jj = 0; jj < 4; ++jj)
                ev[jj] = *reinterpret_cast<const float4*>(Ebase + (size_t)(mg + jj * 128) * CC + Cc);
            const int swz = Cc + (Cc >> 6) * 4;
            #pragma unroll
            for (int h = 0; h < HH; ++h) {
                float4 wv = *reinterpret_cast<const float4*>(&qw_lds[h * 272 + swz]);
                #pragma unroll
                for (int jj = 0; jj < 4; ++jj)
                    acc[h][jj] += ev[jj].x * wv.x + ev[jj].y * wv.y + ev[jj].z * wv.z + ev[jj].w * wv.w;
            }
        }
    }

    // reduce across the 4 cq lanes of each m (lane quads)
    #pragma unroll
    for (int h = 0; h < HH; ++h)
        #pragma unroll
        for (int jj = 0; jj < 4; ++jj) {
            float v = acc[h][jj];
            v += __shfl_xor(v, 1);
            v += __shfl_xor(v, 2);
            acc[h][jj] = v;
        }

    const float scale = 0.17677669529663687f;  // 1/sqrt(32)
    #pragma unroll
    for (int hh = 0; hh < 2; ++hh) {
        int h = 2 * cq + hh;
        #pragma unroll
        for (int jj = 0; jj < 4; ++jj) {
            int m = mg + jj * 128;
            s_lds[h * 516 + m] = (acc[h][jj] + qbp_lds[h]) * scale;
        }
    }
    __syncthreads();

    // softmax: wave w handles head w
    {
        int h = t >> 6, lane = t & 63;
        float vals[8];
        float mx = -1e30f;
        #pragma unroll
        for (int i = 0; i < 8; ++i) {
            vals[i] = s_lds[h * 516 + lane + i * 64];
            mx = fmaxf(mx, vals[i]);
        }
        #pragma unroll
        for (int off = 32; off > 0; off >>= 1) mx = fmaxf(mx, __shfl_xor(mx, off));
        float sum = 0.f;
        #pragma unroll
        for (int i = 0; i < 8; ++i) { vals[i] = __expf(vals[i] - mx); sum += vals[i]; }
        #pragma unroll
        for (int off = 32; off > 0; off >>= 1) sum += __shfl_xor(sum, off);
        float inv = 1.0f / sum;
        #pragma unroll
        for (int i = 0; i < 8; ++i) {
            float p = vals[i] * inv;
            int m = lane + i * 64;
            s_lds[h * 516 + m] = p;
            out_attn[((size_t)h * NN + n) * NN + m] = p;
        }
    }
    __syncthreads();

    // hidden[n, j] = sum_m attn[h, m] * v[m, j],  h = j>>5
    {
        int quad = t & 63;   // output cols j = quad*4 .. quad*4+3
        int slice = t >> 6;  // m slice of 64
        int h = quad >> 3;
        float4 a4 = {0.f, 0.f, 0.f, 0.f};
        const float* vb = vf + quad * 4;
        for (int mm = 0; mm < 64; ++mm) {
            int m = slice * 64 + mm;
            float a = s_lds[h * 516 + m];
            float4 vv = *reinterpret_cast<const float4*>(vb + (size_t)m * CC);
            a4.x += a * vv.x; a4.y += a * vv.y; a4.z += a * vv.z; a4.w += a * vv.w;
        }
        *reinterpret_cast<float4*>(&part_lds[slice * 256 + quad * 4]) = a4;
    }
    __syncthreads();
    if (t < 256) {
        float s = 0.f;
        #pragma unroll
        for (int sl = 0; sl < 8; ++sl) s += part_lds[sl * 256 + t];
        out_hidden[(size_t)n * CC + t] = s;
    }
}

// ---------------- launch ----------------
extern "C" void kernel_launch(void* const* d_in, const int* in_sizes, int n_in,
                              void* d_out, int out_size, void* d_ws, size_t ws_size,
                              hipStream_t stream) {
    const float* xq = (const float*)d_in[0];
    const float* xk = (const float*)d_in[1];
    const float* xv = (const float*)d_in[2];
    const float* E  = (const float*)d_in[3];
    const float* Wq = (const float*)d_in[4];
    const float* bq = (const float*)d_in[5];
    const float* Wk = (const float*)d_in[6];
    const float* bk = (const float*)d_in[7];
    const float* Wv = (const float*)d_in[8];
    const float* bv = (const float*)d_in[9];
    const float* Wp = (const float*)d_in[10];
    const float* bp = (const float*)d_in[11];

    float* ws = (float*)d_ws;
    float* qf  = ws;                        // 512*256
    float* kf  = qf + NN * CC;              // 512*256
    float* vf  = kf + NN * CC;              // 512*256
    float* qw  = vf + NN * CC;              // 512*8*256
    float* qbp = qw + (size_t)NN * HH * CC; // 512*8

    float* out_hidden = (float*)d_out;            // 512*256
    float* out_attn   = out_hidden + NN * CC;     // 8*512*512

    proj_kernel<<<NN / 4, 256, 0, stream>>>(xq, xk, xv, Wq, bq, Wk, bk, Wv, bv, Wp, bp,
                                            qf, kf, vf, qw, qbp);
    attn_kernel<<<NN, 512, 0, stream>>>(E, qf, kf, vf, qw, qbp, out_hidden, out_attn);
}

// Round 2
// 366.206 us; speedup vs baseline: 1.0320x; 1.0320x over previous
//
#include <hip/hip_runtime.h>
#include <math.h>

#define NN 512
#define CC 256
#define HH 8
#define DH 32

// ---------------- Kernel A: projections + Wp-fold ----------------
// grid = 512 (one row n per block), block = 256
__global__ __launch_bounds__(256) void proj_kernel(
    const float* __restrict__ xq, const float* __restrict__ xk, const float* __restrict__ xv,
    const float* __restrict__ Wq, const float* __restrict__ bq,
    const float* __restrict__ Wk, const float* __restrict__ bk,
    const float* __restrict__ Wv, const float* __restrict__ bv,
    const float* __restrict__ Wp, const float* __restrict__ bp,
    float* __restrict__ qf, float* __restrict__ kf, float* __restrict__ vf,
    float* __restrict__ qw, float* __restrict__ qbp)
{
    __shared__ float x_lds[3][CC];
    __shared__ float q_lds[CC];
    const int t = threadIdx.x;
    const int n = blockIdx.x;

    if (t < 192) {
        int X = t >> 6, c4 = (t & 63) * 4;
        const float* xs = (X == 0) ? xq : (X == 1) ? xk : xv;
        *reinterpret_cast<float4*>(&x_lds[X][c4]) =
            *reinterpret_cast<const float4*>(xs + (size_t)n * CC + c4);
    }
    __syncthreads();

    const int j = t;
    {
        float accq = 0.f, acck = 0.f, accv = 0.f;
        const float* wq = Wq + (size_t)j * CC;
        const float* wk = Wk + (size_t)j * CC;
        const float* wv = Wv + (size_t)j * CC;
        #pragma unroll 4
        for (int k4 = 0; k4 < CC / 4; ++k4) {
            float4 a = *reinterpret_cast<const float4*>(wq + k4 * 4);
            float4 b = *reinterpret_cast<const float4*>(wk + k4 * 4);
            float4 d = *reinterpret_cast<const float4*>(wv + k4 * 4);
            const float* x0 = &x_lds[0][k4 * 4];
            const float* x1 = &x_lds[1][k4 * 4];
            const float* x2 = &x_lds[2][k4 * 4];
            accq += x0[0]*a.x + x0[1]*a.y + x0[2]*a.z + x0[3]*a.w;
            acck += x1[0]*b.x + x1[1]*b.y + x1[2]*b.z + x1[3]*b.w;
            accv += x2[0]*d.x + x2[1]*d.y + x2[2]*d.z + x2[3]*d.w;
        }
        float vq = accq + bq[j];
        kf[(size_t)n * CC + j] = acck + bk[j];
        vf[(size_t)n * CC + j] = accv + bv[j];
        qf[(size_t)n * CC + j] = vq;
        q_lds[j] = vq;
    }
    __syncthreads();

    // qw[n][h][j] = sum_c q[h*32+c] * Wp[h*32+c][j]   (coalesced across j)
    #pragma unroll
    for (int h = 0; h < HH; ++h) {
        float acc = 0.f;
        #pragma unroll 8
        for (int cc = 0; cc < DH; ++cc)
            acc += q_lds[h * DH + cc] * Wp[(size_t)(h * DH + cc) * CC + j];
        qw[((size_t)n * HH + h) * CC + j] = acc;
    }
    if (t < HH) {
        float s = 0.f;
        for (int cc = 0; cc < DH; ++cc) s += q_lds[t * DH + cc] * bp[t * DH + cc];
        qbp[(size_t)n * HH + t] = s;
    }
}

// ---------------- Kernel B: fused scores + softmax + hidden ----------------
// one block per n, 512 threads (8 waves); wave w owns rows m in [64w, 64w+64)
__global__ __launch_bounds__(512, 4) void attn_kernel(
    const float* __restrict__ E, const float* __restrict__ qf,
    const float* __restrict__ kf, const float* __restrict__ vf,
    const float* __restrict__ qw, const float* __restrict__ qbp,
    float* __restrict__ out_hidden, float* __restrict__ out_attn)
{
    const int n = blockIdx.x;
    const int t = threadIdx.x;
    const int w = t >> 6;       // wave 0..7
    const int l = t & 63;
    const int r = l >> 4;       // row slot 0..3
    const int c = l & 15;       // 16B chunk within 256B quarter-row

    __shared__ float qw_lds[HH][CC];      // 8 KB
    __shared__ float s_lds[HH][NN + 4];   // 16.1 KB, padded stride
    __shared__ float part_lds[8][CC];     // 8 KB

    // stage qw: 512 threads x 1 float4 = exactly 8 KB, coalesced
    {
        float4 v = *reinterpret_cast<const float4*>(qw + (size_t)n * HH * CC + t * 4);
        *reinterpret_cast<float4*>(&((float*)qw_lds)[t * 4]) = v;
    }
    __syncthreads();

    // q chunks for this lane's column, in registers
    float4 q4[4];
    #pragma unroll
    for (int co = 0; co < 4; ++co)
        q4[co] = *reinterpret_cast<const float4*>(qf + (size_t)n * CC + co * 64 + c * 4);

    const float* Ebase = E + (size_t)n * NN * CC;
    const int mbase = w * 64;

    for (int it = 0; it < 4; ++it) {
        const int m0 = mbase + it * 16 + r;   // rows m0 + 4*jj, jj=0..3
        float acc[HH][4];
        #pragma unroll
        for (int h = 0; h < HH; ++h)
            #pragma unroll
            for (int jj = 0; jj < 4; ++jj) acc[h][jj] = 0.f;

        #pragma unroll
        for (int co = 0; co < 4; ++co) {
            const int o = co * 64 + c * 4;
            float4 e4[4], k4[4];
            #pragma unroll
            for (int jj = 0; jj < 4; ++jj) {
                int m = m0 + 4 * jj;
                e4[jj] = *reinterpret_cast<const float4*>(Ebase + (size_t)m * CC + o);
                k4[jj] = *reinterpret_cast<const float4*>(kf + (size_t)m * CC + o);
            }
            // scores_e contribution: this chunk lies in head 2*co + (c>=8)
            #pragma unroll
            for (int jj = 0; jj < 4; ++jj) {
                float kd = k4[jj].x*q4[co].x + k4[jj].y*q4[co].y +
                           k4[jj].z*q4[co].z + k4[jj].w*q4[co].w;
                acc[2*co  ][jj] += (c & 8) ? 0.f : kd;
                acc[2*co+1][jj] += (c & 8) ? kd : 0.f;
            }
            // scores_p contribution: all 8 heads
            #pragma unroll
            for (int h = 0; h < HH; ++h) {
                float4 wv = *reinterpret_cast<const float4*>(&qw_lds[h][o]);
                #pragma unroll
                for (int jj = 0; jj < 4; ++jj)
                    acc[h][jj] += e4[jj].x*wv.x + e4[jj].y*wv.y +
                                  e4[jj].z*wv.z + e4[jj].w*wv.w;
            }
        }

        // reduce 8 head-partials across the 16 lanes of each row group
        #pragma unroll
        for (int jj = 0; jj < 4; ++jj) {
            float a0 = acc[0][jj], a1 = acc[1][jj], a2 = acc[2][jj], a3 = acc[3][jj];
            float a4 = acc[4][jj], a5 = acc[5][jj], a6 = acc[6][jj], a7 = acc[7][jj];
            const bool b1 = (c & 1), b2 = (c & 2), b4 = (c & 4);
            // stage d=1: heads 8 -> 4
            float t0 = b1 ? a0 : a4, t1 = b1 ? a1 : a5, t2 = b1 ? a2 : a6, t3 = b1 ? a3 : a7;
            float r0 = (b1 ? a4 : a0) + __shfl_xor(t0, 1);
            float r1 = (b1 ? a5 : a1) + __shfl_xor(t1, 1);
            float r2 = (b1 ? a6 : a2) + __shfl_xor(t2, 1);
            float r3 = (b1 ? a7 : a3) + __shfl_xor(t3, 1);
            // stage d=2: 4 -> 2
            t0 = b2 ? r0 : r2; t1 = b2 ? r1 : r3;
            float s0 = (b2 ? r2 : r0) + __shfl_xor(t0, 2);
            float s1 = (b2 ? r3 : r1) + __shfl_xor(t1, 2);
            // stage d=4: 2 -> 1
            t0 = b4 ? s0 : s1;
            float u0 = (b4 ? s1 : s0) + __shfl_xor(t0, 4);
            // stage d=8: fold duplicate half
            u0 += __shfl_xor(u0, 8);
            if (!(c & 8)) {
                int h = (c & 1) * 4 + (c & 2) + ((c >> 2) & 1);
                s_lds[h][m0 + 4 * jj] = u0;   // banks 4h+r: conflict-free
            }
        }
    }
    __syncthreads();

    // softmax: wave w handles head w over all 512 m (bias + scale folded here)
    {
        const int h = w;
        const float qb = qbp[(size_t)n * HH + h];
        const float scale = 0.17677669529663687f;  // 1/sqrt(32)
        float vals[8];
        float mx = -1e30f;
        #pragma unroll
        for (int i = 0; i < 8; ++i) {
            vals[i] = (s_lds[h][l + i * 64] + qb) * scale;
            mx = fmaxf(mx, vals[i]);
        }
        #pragma unroll
        for (int off = 32; off > 0; off >>= 1) mx = fmaxf(mx, __shfl_xor(mx, off));
        float sum = 0.f;
        #pragma unroll
        for (int i = 0; i < 8; ++i) { vals[i] = __expf(vals[i] - mx); sum += vals[i]; }
        #pragma unroll
        for (int off = 32; off > 0; off >>= 1) sum += __shfl_xor(sum, off);
        float inv = 1.0f / sum;
        #pragma unroll
        for (int i = 0; i < 8; ++i) {
            float p = vals[i] * inv;
            int m = l + i * 64;
            s_lds[h][m] = p;
            out_attn[((size_t)h * NN + n) * NN + m] = p;
        }
    }
    __syncthreads();

    // hidden[n][j] = sum_m attn[h][m] * v[m][j], h = j>>5
    {
        const int quad = t & 63;    // output cols quad*4 .. quad*4+3
        const int slice = t >> 6;   // m slice of 64
        const int h = quad >> 3;
        float4 a4 = {0.f, 0.f, 0.f, 0.f};
        const float* vb = vf + quad * 4;
        for (int mm = 0; mm < 64; ++mm) {
            int m = slice * 64 + mm;
            float a = s_lds[h][m];
            float4 vv = *reinterpret_cast<const float4*>(vb + (size_t)m * CC);
            a4.x += a * vv.x; a4.y += a * vv.y; a4.z += a * vv.z; a4.w += a * vv.w;
        }
        *reinterpret_cast<float4*>(&part_lds[slice][quad * 4]) = a4;
    }
    __syncthreads();
    if (t < 256) {
        float s = 0.f;
        #pragma unroll
        for (int sl = 0; sl < 8; ++sl) s += part_lds[sl][t];
        out_hidden[(size_t)n * CC + t] = s;
    }
}

// ---------------- launch ----------------
extern "C" void kernel_launch(void* const* d_in, const int* in_sizes, int n_in,
                              void* d_out, int out_size, void* d_ws, size_t ws_size,
                              hipStream_t stream) {
    const float* xq = (const float*)d_in[0];
    const float* xk = (const float*)d_in[1];
    const float* xv = (const float*)d_in[2];
    const float* E  = (const float*)d_in[3];
    const float* Wq = (const float*)d_in[4];
    const float* bq = (const float*)d_in[5];
    const float* Wk = (const float*)d_in[6];
    const float* bk = (const float*)d_in[7];
    const float* Wv = (const float*)d_in[8];
    const float* bv = (const float*)d_in[9];
    const float* Wp = (const float*)d_in[10];
    const float* bp = (const float*)d_in[11];

    float* ws = (float*)d_ws;
    float* qf  = ws;                        // 512*256
    float* kf  = qf + NN * CC;              // 512*256
    float* vf  = kf + NN * CC;              // 512*256
    float* qw  = vf + NN * CC;              // 512*8*256
    float* qbp = qw + (size_t)NN * HH * CC; // 512*8

    float* out_hidden = (float*)d_out;            // 512*256
    float* out_attn   = out_hidden + NN * CC;     // 8*512*512

    proj_kernel<<<NN, 256, 0, stream>>>(xq, xk, xv, Wq, bq, Wk, bk, Wv, bv, Wp, bp,
                                        qf, kf, vf, qw, qbp);
    attn_kernel<<<NN, 512, 0, stream>>>(E, qf, kf, vf, qw, qbp, out_hidden, out_attn);
}

// Round 3
// 359.895 us; speedup vs baseline: 1.0501x; 1.0175x over previous
//
#include <hip/hip_runtime.h>
#include <math.h>

#define NN 512
#define CC 256
#define HH 8
#define DH 32

// ---------------- Kernel A: projections + Wp-fold ----------------
// grid = 256 (two rows n per block), block = 512
__global__ __launch_bounds__(512) void proj_kernel(
    const float* __restrict__ xq, const float* __restrict__ xk, const float* __restrict__ xv,
    const float* __restrict__ Wq, const float* __restrict__ bq,
    const float* __restrict__ Wk, const float* __restrict__ bk,
    const float* __restrict__ Wv, const float* __restrict__ bv,
    const float* __restrict__ Wp, const float* __restrict__ bp,
    float* __restrict__ qf, float* __restrict__ kf, float* __restrict__ vf,
    float* __restrict__ qw, float* __restrict__ qbp)
{
    __shared__ float x_lds[2][3][CC];
    __shared__ float q_lds[2][CC];
    const int t = threadIdx.x;
    const int n0 = blockIdx.x * 2;

    if (t < 384) {
        int hh = t / 192, rem = t % 192;
        int X = rem >> 6, c4 = (rem & 63) * 4;
        const float* xs = (X == 0) ? xq : (X == 1) ? xk : xv;
        *reinterpret_cast<float4*>(&x_lds[hh][X][c4]) =
            *reinterpret_cast<const float4*>(xs + (size_t)(n0 + hh) * CC + c4);
    }
    __syncthreads();

    const int half = t >> 8, j = t & 255;
    const int n = n0 + half;
    {
        float accq = 0.f, acck = 0.f, accv = 0.f;
        const float* wq = Wq + (size_t)j * CC;
        const float* wk = Wk + (size_t)j * CC;
        const float* wv = Wv + (size_t)j * CC;
        #pragma unroll 4
        for (int k4 = 0; k4 < CC / 4; ++k4) {
            float4 a = *reinterpret_cast<const float4*>(wq + k4 * 4);
            float4 b = *reinterpret_cast<const float4*>(wk + k4 * 4);
            float4 d = *reinterpret_cast<const float4*>(wv + k4 * 4);
            const float* x0 = &x_lds[half][0][k4 * 4];
            const float* x1 = &x_lds[half][1][k4 * 4];
            const float* x2 = &x_lds[half][2][k4 * 4];
            accq += x0[0]*a.x + x0[1]*a.y + x0[2]*a.z + x0[3]*a.w;
            acck += x1[0]*b.x + x1[1]*b.y + x1[2]*b.z + x1[3]*b.w;
            accv += x2[0]*d.x + x2[1]*d.y + x2[2]*d.z + x2[3]*d.w;
        }
        float vq = accq + bq[j];
        kf[(size_t)n * CC + j] = acck + bk[j];
        vf[(size_t)n * CC + j] = accv + bv[j];
        qf[(size_t)n * CC + j] = vq;
        q_lds[half][j] = vq;
    }
    __syncthreads();

    // qw[n][h][j] = sum_c q[h*32+c] * Wp[h*32+c][j]
    #pragma unroll
    for (int h = 0; h < HH; ++h) {
        float acc = 0.f;
        #pragma unroll 8
        for (int cc = 0; cc < DH; ++cc)
            acc += q_lds[half][h * DH + cc] * Wp[(size_t)(h * DH + cc) * CC + j];
        qw[((size_t)n * HH + h) * CC + j] = acc;
    }
    if (t < 16) {
        int hf = t >> 3, h = t & 7;
        float s = 0.f;
        for (int cc = 0; cc < DH; ++cc) s += q_lds[hf][h * DH + cc] * bp[h * DH + cc];
        qbp[(size_t)(n0 + hf) * HH + h] = s;
    }
}

// ---------------- Kernel A2: scores_e = q . k^T per head ----------------
// grid = 512: b = h*64 + nt*8 + mt; 64x64 tile; writes esc[h][n][m] (d_out attn region)
__global__ __launch_bounds__(256) void escore_kernel(
    const float* __restrict__ qf, const float* __restrict__ kf, float* __restrict__ esc)
{
    const int b = blockIdx.x;
    const int h = b >> 6, nt = (b >> 3) & 7, mt = b & 7;
    const int n0 = nt * 64, m0 = mt * 64;
    const int t = threadIdx.x;

    __shared__ float q_t[64][33];
    __shared__ float k_t[64][33];

    #pragma unroll
    for (int it = 0; it < 2; ++it) {
        int idx = t + it * 256;
        int row = idx >> 3, c4 = (idx & 7) * 4;
        float4 qv = *reinterpret_cast<const float4*>(qf + (size_t)(n0 + row) * CC + h * DH + c4);
        float4 kv = *reinterpret_cast<const float4*>(kf + (size_t)(m0 + row) * CC + h * DH + c4);
        q_t[row][c4] = qv.x; q_t[row][c4+1] = qv.y; q_t[row][c4+2] = qv.z; q_t[row][c4+3] = qv.w;
        k_t[row][c4] = kv.x; k_t[row][c4+1] = kv.y; k_t[row][c4+2] = kv.z; k_t[row][c4+3] = kv.w;
    }
    __syncthreads();

    const int tx = t & 15, ty = t >> 4;
    float acc[4][4];
    #pragma unroll
    for (int i = 0; i < 4; ++i)
        #pragma unroll
        for (int jq = 0; jq < 4; ++jq) acc[i][jq] = 0.f;

    for (int cc = 0; cc < DH; ++cc) {
        float qa[4], kb[4];
        #pragma unroll
        for (int i = 0; i < 4; ++i) qa[i] = q_t[ty * 4 + i][cc];
        #pragma unroll
        for (int jq = 0; jq < 4; ++jq) kb[jq] = k_t[tx * 4 + jq][cc];
        #pragma unroll
        for (int i = 0; i < 4; ++i)
            #pragma unroll
            for (int jq = 0; jq < 4; ++jq) acc[i][jq] += qa[i] * kb[jq];
    }

    #pragma unroll
    for (int i = 0; i < 4; ++i) {
        float4 v = {acc[i][0], acc[i][1], acc[i][2], acc[i][3]};
        *reinterpret_cast<float4*>(esc + ((size_t)h * NN + n0 + ty * 4 + i) * NN + m0 + tx * 4) = v;
    }
}

// ---------------- Kernel B: E-stream + softmax (in-place on esc/attn) ----------------
// one block per n, 512 threads (8 waves); wave w owns rows m in [64w, 64w+64)
__global__ __launch_bounds__(512, 4) void attn_kernel(
    const float* __restrict__ E, const float* __restrict__ qw,
    const float* __restrict__ qbp, float* __restrict__ attn_io)
{
    const int n = blockIdx.x;
    const int t = threadIdx.x;
    const int w = t >> 6, l = t & 63;
    const int r = l >> 4, c = l & 15;

    __shared__ float qw_lds[HH][CC];      // 8 KB
    __shared__ float s_lds[HH][NN + 4];   // 16.1 KB

    // stage qw: 512 threads x 1 float4 = 8 KB, coalesced
    {
        float4 v = *reinterpret_cast<const float4*>(qw + (size_t)n * HH * CC + t * 4);
        reinterpret_cast<float4*>(qw_lds)[t] = v;
    }
    // seed s_lds with scores_e for head w (written by escore_kernel)
    {
        const float* ep = attn_io + ((size_t)w * NN + n) * NN + l * 8;
        float4 a = *reinterpret_cast<const float4*>(ep);
        float4 b = *reinterpret_cast<const float4*>(ep + 4);
        *reinterpret_cast<float4*>(&s_lds[w][l * 8]) = a;
        *reinterpret_cast<float4*>(&s_lds[w][l * 8 + 4]) = b;
    }
    __syncthreads();

    const float* Ebase = E + (size_t)n * NN * CC;
    const int mbase = w * 64;

    // 2-deep software-pipelined E stream; 16 (g,co) phases, 4 rows x 16B each
    float4 ebuf[2][4];
    #pragma unroll
    for (int it = 0; it < 4; ++it)
        ebuf[0][it] = *reinterpret_cast<const float4*>(
            Ebase + (size_t)(mbase + it * 4 + r) * CC + c * 4);

    #pragma unroll
    for (int g = 0; g < 4; ++g) {
        float acc[4][HH];
        #pragma unroll
        for (int it = 0; it < 4; ++it)
            #pragma unroll
            for (int h = 0; h < HH; ++h) acc[it][h] = 0.f;

        #pragma unroll
        for (int co = 0; co < 4; ++co) {
            const int gc = g * 4 + co;
            // prefetch next phase
            if (gc + 1 < 16) {
                const int gn = (gc + 1) >> 2, cn = (gc + 1) & 3;
                #pragma unroll
                for (int it = 0; it < 4; ++it)
                    ebuf[(gc + 1) & 1][it] = *reinterpret_cast<const float4*>(
                        Ebase + (size_t)(mbase + gn * 16 + it * 4 + r) * CC + cn * 64 + c * 4);
            }
            const int o = co * 64 + c * 4;
            float4 wv[HH];
            #pragma unroll
            for (int h = 0; h < HH; ++h)
                wv[h] = *reinterpret_cast<const float4*>(&qw_lds[h][o]);
            #pragma unroll
            for (int it = 0; it < 4; ++it) {
                float4 e4 = ebuf[gc & 1][it];
                #pragma unroll
                for (int h = 0; h < HH; ++h)
                    acc[it][h] += e4.x * wv[h].x + e4.y * wv[h].y +
                                  e4.z * wv[h].z + e4.w * wv[h].w;
            }
        }

        // reduce 8 head-partials across 16 lanes per row, add into s_lds
        #pragma unroll
        for (int it = 0; it < 4; ++it) {
            float a0 = acc[it][0], a1 = acc[it][1], a2 = acc[it][2], a3 = acc[it][3];
            float a4 = acc[it][4], a5 = acc[it][5], a6 = acc[it][6], a7 = acc[it][7];
            const bool b1 = (c & 1), b2 = (c & 2), b4 = (c & 4);
            float t0 = b1 ? a0 : a4, t1 = b1 ? a1 : a5, t2 = b1 ? a2 : a6, t3 = b1 ? a3 : a7;
            float r0 = (b1 ? a4 : a0) + __shfl_xor(t0, 1);
            float r1 = (b1 ? a5 : a1) + __shfl_xor(t1, 1);
            float r2 = (b1 ? a6 : a2) + __shfl_xor(t2, 1);
            float r3 = (b1 ? a7 : a3) + __shfl_xor(t3, 1);
            t0 = b2 ? r0 : r2; t1 = b2 ? r1 : r3;
            float s0 = (b2 ? r2 : r0) + __shfl_xor(t0, 2);
            float s1 = (b2 ? r3 : r1) + __shfl_xor(t1, 2);
            t0 = b4 ? s0 : s1;
            float u0 = (b4 ? s1 : s0) + __shfl_xor(t0, 4);
            u0 += __shfl_xor(u0, 8);
            if (!(c & 8)) {
                int h = (c & 1) * 4 + (c & 2) + ((c >> 2) & 1);
                int row = mbase + g * 16 + it * 4 + r;
                s_lds[h][row] += u0;
            }
        }
    }
    __syncthreads();

    // softmax: wave w handles head w over all 512 m
    {
        const int h = w;
        const float qb = qbp[(size_t)n * HH + h];
        const float scale = 0.17677669529663687f;  // 1/sqrt(32)
        float vals[8];
        float mx = -1e30f;
        #pragma unroll
        for (int i = 0; i < 8; ++i) {
            vals[i] = (s_lds[h][l + i * 64] + qb) * scale;
            mx = fmaxf(mx, vals[i]);
        }
        #pragma unroll
        for (int off = 32; off > 0; off >>= 1) mx = fmaxf(mx, __shfl_xor(mx, off));
        float sum = 0.f;
        #pragma unroll
        for (int i = 0; i < 8; ++i) { vals[i] = __expf(vals[i] - mx); sum += vals[i]; }
        #pragma unroll
        for (int off = 32; off > 0; off >>= 1) sum += __shfl_xor(sum, off);
        float inv = 1.0f / sum;
        #pragma unroll
        for (int i = 0; i < 8; ++i)
            attn_io[((size_t)h * NN + n) * NN + l + i * 64] = vals[i] * inv;
    }
}

// ---------------- Kernel C: hidden = attn @ v ----------------
// grid = 128 (4 n-rows per block), block = 256
__global__ __launch_bounds__(256) void hidden_kernel(
    const float* __restrict__ attn, const float* __restrict__ vf,
    float* __restrict__ out_hidden)
{
    const int t = threadIdx.x;
    const int n = blockIdx.x * 4 + (t >> 6);
    const int quad = t & 63;               // output cols quad*4..quad*4+3
    const int h = quad >> 3;
    const float* ap = attn + ((size_t)h * NN + n) * NN;
    const float* vp = vf + quad * 4;
    float4 acc = {0.f, 0.f, 0.f, 0.f};
    for (int m = 0; m < NN; m += 4) {
        float4 a4 = *reinterpret_cast<const float4*>(ap + m);
        float4 v0 = *reinterpret_cast<const float4*>(vp + (size_t)(m    ) * CC);
        float4 v1 = *reinterpret_cast<const float4*>(vp + (size_t)(m + 1) * CC);
        float4 v2 = *reinterpret_cast<const float4*>(vp + (size_t)(m + 2) * CC);
        float4 v3 = *reinterpret_cast<const float4*>(vp + (size_t)(m + 3) * CC);
        acc.x += a4.x * v0.x + a4.y * v1.x + a4.z * v2.x + a4.w * v3.x;
        acc.y += a4.x * v0.y + a4.y * v1.y + a4.z * v2.y + a4.w * v3.y;
        acc.z += a4.x * v0.z + a4.y * v1.z + a4.z * v2.z + a4.w * v3.z;
        acc.w += a4.x * v0.w + a4.y * v1.w + a4.z * v2.w + a4.w * v3.w;
    }
    *reinterpret_cast<float4*>(out_hidden + (size_t)n * CC + quad * 4) = acc;
}

// ---------------- launch ----------------
extern "C" void kernel_launch(void* const* d_in, const int* in_sizes, int n_in,
                              void* d_out, int out_size, void* d_ws, size_t ws_size,
                              hipStream_t stream) {
    const float* xq = (const float*)d_in[0];
    const float* xk = (const float*)d_in[1];
    const float* xv = (const float*)d_in[2];
    const float* E  = (const float*)d_in[3];
    const float* Wq = (const float*)d_in[4];
    const float* bq = (const float*)d_in[5];
    const float* Wk = (const float*)d_in[6];
    const float* bk = (const float*)d_in[7];
    const float* Wv = (const float*)d_in[8];
    const float* bv = (const float*)d_in[9];
    const float* Wp = (const float*)d_in[10];
    const float* bp = (const float*)d_in[11];

    float* ws = (float*)d_ws;
    float* qf  = ws;                        // 512*256
    float* kf  = qf + NN * CC;              // 512*256
    float* vf  = kf + NN * CC;              // 512*256
    float* qw  = vf + NN * CC;              // 512*8*256
    float* qbp = qw + (size_t)NN * HH * CC; // 512*8

    float* out_hidden = (float*)d_out;            // 512*256
    float* out_attn   = out_hidden + NN * CC;     // 8*512*512 (esc staged here too)

    proj_kernel<<<NN / 2, 512, 0, stream>>>(xq, xk, xv, Wq, bq, Wk, bk, Wv, bv, Wp, bp,
                                            qf, kf, vf, qw, qbp);
    escore_kernel<<<512, 256, 0, stream>>>(qf, kf, out_attn);
    attn_kernel<<<NN, 512, 0, stream>>>(E, qw, qbp, out_attn);
    hidden_kernel<<<128, 256, 0, stream>>>(out_attn, vf, out_hidden);
}

// Round 4
// 140.476 us; speedup vs baseline: 2.6903x; 2.5620x over previous
//
#include <hip/hip_runtime.h>
#include <math.h>

#define NN 512
#define CC 256
#define HH 8
#define DH 32

// ---------------- Kernel A: projections + Wp-fold ----------------
// grid = 256 (two rows n per block), block = 512
__global__ __launch_bounds__(512) void proj_kernel(
    const float* __restrict__ xq, const float* __restrict__ xk, const float* __restrict__ xv,
    const float* __restrict__ Wq, const float* __restrict__ bq,
    const float* __restrict__ Wk, const float* __restrict__ bk,
    const float* __restrict__ Wv, const float* __restrict__ bv,
    const float* __restrict__ Wp, const float* __restrict__ bp,
    float* __restrict__ qf, float* __restrict__ kf, float* __restrict__ vf,
    float* __restrict__ qw, float* __restrict__ qbp)
{
    __shared__ float x_lds[2][3][CC];
    __shared__ float q_lds[2][CC];
    const int t = threadIdx.x;
    const int n0 = blockIdx.x * 2;

    if (t < 384) {
        int hh = t / 192, rem = t % 192;
        int X = rem >> 6, c4 = (rem & 63) * 4;
        const float* xs = (X == 0) ? xq : (X == 1) ? xk : xv;
        *reinterpret_cast<float4*>(&x_lds[hh][X][c4]) =
            *reinterpret_cast<const float4*>(xs + (size_t)(n0 + hh) * CC + c4);
    }
    __syncthreads();

    const int half = t >> 8, j = t & 255;
    const int n = n0 + half;
    {
        float accq = 0.f, acck = 0.f, accv = 0.f;
        const float* wq = Wq + (size_t)j * CC;
        const float* wk = Wk + (size_t)j * CC;
        const float* wv = Wv + (size_t)j * CC;
        #pragma unroll 4
        for (int k4 = 0; k4 < CC / 4; ++k4) {
            float4 a = *reinterpret_cast<const float4*>(wq + k4 * 4);
            float4 b = *reinterpret_cast<const float4*>(wk + k4 * 4);
            float4 d = *reinterpret_cast<const float4*>(wv + k4 * 4);
            const float* x0 = &x_lds[half][0][k4 * 4];
            const float* x1 = &x_lds[half][1][k4 * 4];
            const float* x2 = &x_lds[half][2][k4 * 4];
            accq += x0[0]*a.x + x0[1]*a.y + x0[2]*a.z + x0[3]*a.w;
            acck += x1[0]*b.x + x1[1]*b.y + x1[2]*b.z + x1[3]*b.w;
            accv += x2[0]*d.x + x2[1]*d.y + x2[2]*d.z + x2[3]*d.w;
        }
        float vq = accq + bq[j];
        kf[(size_t)n * CC + j] = acck + bk[j];
        vf[(size_t)n * CC + j] = accv + bv[j];
        qf[(size_t)n * CC + j] = vq;
        q_lds[half][j] = vq;
    }
    __syncthreads();

    // qw[n][h][j] = sum_c q[h*32+c] * Wp[h*32+c][j]
    #pragma unroll
    for (int h = 0; h < HH; ++h) {
        float acc = 0.f;
        #pragma unroll 8
        for (int cc = 0; cc < DH; ++cc)
            acc += q_lds[half][h * DH + cc] * Wp[(size_t)(h * DH + cc) * CC + j];
        qw[((size_t)n * HH + h) * CC + j] = acc;
    }
    if (t < 16) {
        int hf = t >> 3, h = t & 7;
        float s = 0.f;
        for (int cc = 0; cc < DH; ++cc) s += q_lds[hf][h * DH + cc] * bp[h * DH + cc];
        qbp[(size_t)(n0 + hf) * HH + h] = s;
    }
}

// ---------------- Kernel A2: scores_e = q . k^T per head ----------------
// grid = 512: b = h*64 + nt*8 + mt; 64x64 tile; writes esc[h][n][m] (d_out attn region)
__global__ __launch_bounds__(256) void escore_kernel(
    const float* __restrict__ qf, const float* __restrict__ kf, float* __restrict__ esc)
{
    const int b = blockIdx.x;
    const int h = b >> 6, nt = (b >> 3) & 7, mt = b & 7;
    const int n0 = nt * 64, m0 = mt * 64;
    const int t = threadIdx.x;

    __shared__ float q_t[64][33];
    __shared__ float k_t[64][33];

    #pragma unroll
    for (int it = 0; it < 2; ++it) {
        int idx = t + it * 256;
        int row = idx >> 3, c4 = (idx & 7) * 4;
        float4 qv = *reinterpret_cast<const float4*>(qf + (size_t)(n0 + row) * CC + h * DH + c4);
        float4 kv = *reinterpret_cast<const float4*>(kf + (size_t)(m0 + row) * CC + h * DH + c4);
        q_t[row][c4] = qv.x; q_t[row][c4+1] = qv.y; q_t[row][c4+2] = qv.z; q_t[row][c4+3] = qv.w;
        k_t[row][c4] = kv.x; k_t[row][c4+1] = kv.y; k_t[row][c4+2] = kv.z; k_t[row][c4+3] = kv.w;
    }
    __syncthreads();

    const int tx = t & 15, ty = t >> 4;
    float acc[4][4];
    #pragma unroll
    for (int i = 0; i < 4; ++i)
        #pragma unroll
        for (int jq = 0; jq < 4; ++jq) acc[i][jq] = 0.f;

    for (int cc = 0; cc < DH; ++cc) {
        float qa[4], kb[4];
        #pragma unroll
        for (int i = 0; i < 4; ++i) qa[i] = q_t[ty * 4 + i][cc];
        #pragma unroll
        for (int jq = 0; jq < 4; ++jq) kb[jq] = k_t[tx * 4 + jq][cc];
        #pragma unroll
        for (int i = 0; i < 4; ++i)
            #pragma unroll
            for (int jq = 0; jq < 4; ++jq) acc[i][jq] += qa[i] * kb[jq];
    }

    #pragma unroll
    for (int i = 0; i < 4; ++i) {
        float4 v = {acc[i][0], acc[i][1], acc[i][2], acc[i][3]};
        *reinterpret_cast<float4*>(esc + ((size_t)h * NN + n0 + ty * 4 + i) * NN + m0 + tx * 4) = v;
    }
}

// ---------------- Kernel B: E-stream + softmax + hidden (fused) ----------------
// one block per n, 512 threads (8 waves); wave w owns rows m in [64w, 64w+64)
__global__ __launch_bounds__(512, 2) void attn_kernel(
    const float* __restrict__ E, const float* __restrict__ qw,
    const float* __restrict__ qbp, const float* __restrict__ vf,
    float* __restrict__ attn_io, float* __restrict__ out_hidden)
{
    const int n = blockIdx.x;
    const int t = threadIdx.x;
    const int w = t >> 6, l = t & 63;
    const int r = l >> 4, c = l & 15;

    __shared__ float qw_lds[HH][CC];      // 8 KB; reused as hidden partials later
    __shared__ float s_lds[HH][NN + 4];   // 16.1 KB

    // stage qw: 512 threads x 1 float4 = 8 KB, coalesced
    {
        float4 v = *reinterpret_cast<const float4*>(qw + (size_t)n * HH * CC + t * 4);
        reinterpret_cast<float4*>(qw_lds)[t] = v;
    }
    // seed s_lds with scores_e for head w (written by escore_kernel)
    {
        const float* ep = attn_io + ((size_t)w * NN + n) * NN + l * 8;
        float4 a = *reinterpret_cast<const float4*>(ep);
        float4 b = *reinterpret_cast<const float4*>(ep + 4);
        *reinterpret_cast<float4*>(&s_lds[w][l * 8]) = a;
        *reinterpret_cast<float4*>(&s_lds[w][l * 8 + 4]) = b;
    }
    __syncthreads();

    const float* Ebase = E + (size_t)n * NN * CC;
    const int mbase = w * 64;

    #pragma unroll
    for (int g = 0; g < 4; ++g) {
        float acc[4][HH];
        #pragma unroll
        for (int it = 0; it < 4; ++it)
            #pragma unroll
            for (int h = 0; h < HH; ++h) acc[it][h] = 0.f;

        #pragma unroll
        for (int co = 0; co < 4; ++co) {
            const int o = co * 64 + c * 4;
            float4 e4[4];
            #pragma unroll
            for (int it = 0; it < 4; ++it)
                e4[it] = *reinterpret_cast<const float4*>(
                    Ebase + (size_t)(mbase + g * 16 + it * 4 + r) * CC + o);
            #pragma unroll
            for (int h = 0; h < HH; ++h) {
                float4 wv = *reinterpret_cast<const float4*>(&qw_lds[h][o]);
                #pragma unroll
                for (int it = 0; it < 4; ++it)
                    acc[it][h] += e4[it].x * wv.x + e4[it].y * wv.y +
                                  e4[it].z * wv.z + e4[it].w * wv.w;
            }
        }

        // reduce 8 head-partials across 16 lanes per row, accumulate into s_lds
        #pragma unroll
        for (int it = 0; it < 4; ++it) {
            float a0 = acc[it][0], a1 = acc[it][1], a2 = acc[it][2], a3 = acc[it][3];
            float a4 = acc[it][4], a5 = acc[it][5], a6 = acc[it][6], a7 = acc[it][7];
            const bool b1 = (c & 1), b2 = (c & 2), b4 = (c & 4);
            float t0 = b1 ? a0 : a4, t1 = b1 ? a1 : a5, t2 = b1 ? a2 : a6, t3 = b1 ? a3 : a7;
            float r0 = (b1 ? a4 : a0) + __shfl_xor(t0, 1);
            float r1 = (b1 ? a5 : a1) + __shfl_xor(t1, 1);
            float r2 = (b1 ? a6 : a2) + __shfl_xor(t2, 1);
            float r3 = (b1 ? a7 : a3) + __shfl_xor(t3, 1);
            t0 = b2 ? r0 : r2; t1 = b2 ? r1 : r3;
            float s0 = (b2 ? r2 : r0) + __shfl_xor(t0, 2);
            float s1 = (b2 ? r3 : r1) + __shfl_xor(t1, 2);
            t0 = b4 ? s0 : s1;
            float u0 = (b4 ? s1 : s0) + __shfl_xor(t0, 4);
            u0 += __shfl_xor(u0, 8);
            if (!(c & 8)) {
                int h = (c & 1) * 4 + (c & 2) + ((c >> 2) & 1);
                int row = mbase + g * 16 + it * 4 + r;
                s_lds[h][row] += u0;   // banks 4h+r: conflict-free
            }
        }
    }
    __syncthreads();

    // softmax: wave w handles head w over all 512 m (bias + scale folded)
    {
        const int h = w;
        const float qb = qbp[(size_t)n * HH + h];
        const float scale = 0.17677669529663687f;  // 1/sqrt(32)
        float vals[8];
        float mx = -1e30f;
        #pragma unroll
        for (int i = 0; i < 8; ++i) {
            vals[i] = (s_lds[h][l + i * 64] + qb) * scale;
            mx = fmaxf(mx, vals[i]);
        }
        #pragma unroll
        for (int off = 32; off > 0; off >>= 1) mx = fmaxf(mx, __shfl_xor(mx, off));
        float sum = 0.f;
        #pragma unroll
        for (int i = 0; i < 8; ++i) { vals[i] = __expf(vals[i] - mx); sum += vals[i]; }
        #pragma unroll
        for (int off = 32; off > 0; off >>= 1) sum += __shfl_xor(sum, off);
        float inv = 1.0f / sum;
        #pragma unroll
        for (int i = 0; i < 8; ++i) {
            float p = vals[i] * inv;
            int m = l + i * 64;
            s_lds[h][m] = p;
            attn_io[((size_t)h * NN + n) * NN + m] = p;
        }
    }
    __syncthreads();

    // hidden[n][j] = sum_m attn[h][m] * v[m][j], h = j>>5 (v is L2-resident, 512 KB)
    {
        float* part = &qw_lds[0][0];       // reuse qw_lds (8 KB) as partial buffer
        const int quad = t & 63;           // output cols quad*4..quad*4+3
        const int slice = w;               // m slice of 64
        const int h = quad >> 3;
        float4 a4 = {0.f, 0.f, 0.f, 0.f};
        const float* vb = vf + quad * 4;
        for (int mm = 0; mm < 64; ++mm) {
            int m = slice * 64 + mm;
            float a = s_lds[h][m];
            float4 vv = *reinterpret_cast<const float4*>(vb + (size_t)m * CC);
            a4.x += a * vv.x; a4.y += a * vv.y; a4.z += a * vv.z; a4.w += a * vv.w;
        }
        __syncthreads();                    // qw_lds reads are long done; re-purpose
        *reinterpret_cast<float4*>(&part[slice * 256 + quad * 4]) = a4;
    }
    __syncthreads();
    if (t < 256) {
        const float* part = &qw_lds[0][0];
        float s = 0.f;
        #pragma unroll
        for (int sl = 0; sl < 8; ++sl) s += part[sl * 256 + t];
        out_hidden[(size_t)n * CC + t] = s;
    }
}

// ---------------- launch ----------------
extern "C" void kernel_launch(void* const* d_in, const int* in_sizes, int n_in,
                              void* d_out, int out_size, void* d_ws, size_t ws_size,
                              hipStream_t stream) {
    const float* xq = (const float*)d_in[0];
    const float* xk = (const float*)d_in[1];
    const float* xv = (const float*)d_in[2];
    const float* E  = (const float*)d_in[3];
    const float* Wq = (const float*)d_in[4];
    const float* bq = (const float*)d_in[5];
    const float* Wk = (const float*)d_in[6];
    const float* bk = (const float*)d_in[7];
    const float* Wv = (const float*)d_in[8];
    const float* bv = (const float*)d_in[9];
    const float* Wp = (const float*)d_in[10];
    const float* bp = (const float*)d_in[11];

    float* ws = (float*)d_ws;
    float* qf  = ws;                        // 512*256
    float* kf  = qf + NN * CC;              // 512*256
    float* vf  = kf + NN * CC;              // 512*256
    float* qw  = vf + NN * CC;              // 512*8*256
    float* qbp = qw + (size_t)NN * HH * CC; // 512*8

    float* out_hidden = (float*)d_out;            // 512*256
    float* out_attn   = out_hidden + NN * CC;     // 8*512*512 (esc staged here too)

    proj_kernel<<<NN / 2, 512, 0, stream>>>(xq, xk, xv, Wq, bq, Wk, bk, Wv, bv, Wp, bp,
                                            qf, kf, vf, qw, qbp);
    escore_kernel<<<512, 256, 0, stream>>>(qf, kf, out_attn);
    attn_kernel<<<NN, 512, 0, stream>>>(E, qw, qbp, vf, out_attn, out_hidden);
}